// Round 7
// baseline (220.426 us; speedup 1.0000x reference)
//
#include <hip/hip_runtime.h>
#include <hip/hip_bf16.h>

#define H_DIM 512
#define N_HEADS 8
#define HEAD_DIM 64
#define NBATCH 16

typedef __attribute__((ext_vector_type(8))) short short8;   // 8 bf16 (4 VGPRs)
typedef __attribute__((ext_vector_type(4))) float floatx4;  // MFMA acc

typedef unsigned short us16;

// 3-bit row swizzle for XOR'd LDS slots (structurally conflict-free b128)
#define SW3(r) ((((r) >> 1) & 3) | (((r) & 1) << 2))

// head-major channel permutation: c (=d*8+h) -> c' (=h*64+d)
#define PERMC(c) ((((c) & 7) << 6) | ((c) >> 3))
// inverse: c' -> c
#define IPERMC(cp) ((((cp) & 63) << 3) | ((cp) >> 6))

__device__ inline unsigned short f2bf(float f) {
  unsigned int u = __float_as_uint(f);
  unsigned int r = (u + 0x7fffu + ((u >> 16) & 1u)) >> 16;  // RNE
  return (unsigned short)r;
}

// async global->LDS, 16B/lane; lds dest = wave-uniform base + lane*16
__device__ inline void gld16(const us16* g, us16* l) {
  __builtin_amdgcn_global_load_lds(
      (const __attribute__((address_space(1))) void*)g,
      (__attribute__((address_space(3))) void*)l, 16, 0, 0);
}

// ---------------------------------------------------------------------------
// prep0: ONLY the QKV weight casts (Wq/Wk row-permuted head-major, Wv
// straight) + BN-stat zero. 768 blocks: rg = blk>>8 selects region; each
// region 262144 elems, 4/thread. Activations are no longer cast at all —
// the GEMMs reg-stage fp32 directly (same f2bf RNE => bit-identical).
// ---------------------------------------------------------------------------
__global__ __launch_bounds__(256) void prep0(
    const float* __restrict__ Wq, const float* __restrict__ Wk,
    const float* __restrict__ Wv,
    us16* __restrict__ Wqb, us16* __restrict__ Wkv, float* __restrict__ st) {
  const int blk = blockIdx.x, t = threadIdx.x;
  if (blk == 0) {
    float4 z = make_float4(0.f, 0.f, 0.f, 0.f);
    ((float4*)st)[t] = z;
    ((float4*)st)[t + 256] = z;
  }
  const int rg = blk >> 8;
  const float* sp = (rg == 0) ? Wq : (rg == 1) ? Wk : Wv;
  us16* dp = (rg == 0) ? Wqb : (rg == 1) ? Wkv : (Wkv + 262144);
  const int i = (((blk & 255) << 8) + t) << 2;  // 0..262140
  float4 v = *(const float4*)(sp + i);
  ushort4 o;
  o.x = f2bf(v.x); o.y = f2bf(v.y); o.z = f2bf(v.z); o.w = f2bf(v.w);
  int jd = (rg < 2) ? ((PERMC(i >> 9) << 9) + (i & 511)) : i;
  *(ushort4*)(dp + jd) = o;
}

// ---------------------------------------------------------------------------
// 64x128 GEMM body, A reg-staged from FP32 (ffn2bn-proven pattern, identity
// transform), B via gld16 (bf16 weights). K=512 (nk=8). Per chunk: 4 fp32
// dwordx4 A-loads + 4 B-gld16 = 8 vm ops; counted wait vmcnt(8) keeps the
// next chunk in flight. 48 KB LDS -> 3 blocks/CU.
// modes: 1 bf16 row-major [M][512] head-major cols; 4 fused K/V.
// ---------------------------------------------------------------------------
__device__ inline void qkv_body(
    const float* __restrict__ actF, const us16* __restrict__ W,
    const float* __restrict__ bias0, const float* __restrict__ bias1,
    void* __restrict__ C0, void* __restrict__ C1,
    int M, int mode, int bx, int by, us16* As, us16* Bs) {
  const int t = threadIdx.x, w = t >> 6, lane = t & 63;
  const int lane15 = lane & 15, quad = lane >> 4;
  const int bm = bx * 64, bn = by * 128;
  const int lrow = lane >> 3, sl = lane & 7;
  const int arow = t >> 2, ac4 = (t & 3) * 16, s0 = (t & 3) * 2;

  floatx4 acc[4][2];
#pragma unroll
  for (int a = 0; a < 4; ++a)
#pragma unroll
    for (int c = 0; c < 2; ++c) acc[a][c] = (floatx4){0.f, 0.f, 0.f, 0.f};

#define QALOAD(dst, ii)                                                      \
  {                                                                          \
    const float* p_ = actF + (size_t)(bm + arow) * 512 + ((ii) << 6) + ac4;  \
    dst[0] = *(const float4*)(p_);                                           \
    dst[1] = *(const float4*)(p_ + 4);                                       \
    dst[2] = *(const float4*)(p_ + 8);                                       \
    dst[3] = *(const float4*)(p_ + 12);                                      \
  }
#define QBISS(ii, bb)                                                        \
  {                                                                          \
    int k0 = (ii) << 6;                                                      \
    _Pragma("unroll")                                                        \
    for (int p = 0; p < 4; ++p) {                                            \
      int rbase = p * 32 + w * 8;                                            \
      int row = rbase + lrow;                                                \
      int kg = sl ^ SW3(row);                                                \
      gld16(W + (size_t)(bn + row) * 512 + k0 + kg * 8,                      \
            Bs + (bb) * 8192 + rbase * 64);                                  \
    }                                                                        \
  }

  float4 areg[2][4];
  QALOAD(areg[0], 0);
  QBISS(0, 0);
  asm volatile("" ::: "memory");
  QALOAD(areg[1], 1);
  QBISS(1, 1);

#pragma unroll
  for (int i = 0; i < 8; ++i) {
    const int cur = i & 1;
    if (i < 7) {
      asm volatile("s_waitcnt vmcnt(8)" ::: "memory");
    } else {
      asm volatile("s_waitcnt vmcnt(0)" ::: "memory");
    }
    {  // cvt A chunk i -> As[cur] (identity; same RNE as old prep cast)
      __align__(16) us16 vv[16];
#pragma unroll
      for (int q = 0; q < 4; ++q)
#pragma unroll
        for (int j = 0; j < 4; ++j)
          vv[q * 4 + j] = f2bf(((const float*)&areg[cur][q])[j]);
      us16* base = As + cur * 4096 + arow * 64;
      *(short8*)(base + ((s0 ^ SW3(arow)) * 8)) = *(short8*)&vv[0];
      *(short8*)(base + (((s0 + 1) ^ SW3(arow)) * 8)) = *(short8*)&vv[8];
    }
    asm volatile("s_waitcnt lgkmcnt(0)" ::: "memory");
    __builtin_amdgcn_s_barrier();
    asm volatile("" ::: "memory");
#pragma unroll
    for (int kh = 0; kh < 2; ++kh) {
      const int g = kh * 4 + quad;
      short8 a_[4], b_[2];
#pragma unroll
      for (int mt = 0; mt < 4; ++mt) {
        int r = mt * 16 + lane15;
        a_[mt] = *(const short8*)(As + cur * 4096 + r * 64 + (g ^ SW3(r)) * 8);
      }
#pragma unroll
      for (int nt = 0; nt < 2; ++nt) {
        int c = w * 32 + nt * 16 + lane15;
        b_[nt] = *(const short8*)(Bs + cur * 8192 + c * 64 + (g ^ SW3(c)) * 8);
      }
#pragma unroll
      for (int mt = 0; mt < 4; ++mt)
#pragma unroll
        for (int nt = 0; nt < 2; ++nt)
          acc[mt][nt] = __builtin_amdgcn_mfma_f32_16x16x32_bf16(
              a_[mt], b_[nt], acc[mt][nt], 0, 0, 0);
    }
    asm volatile("" ::: "memory");
    __builtin_amdgcn_s_barrier();
    asm volatile("" ::: "memory");
    if (i + 2 < 8) {
      QALOAD(areg[cur], i + 2);
      QBISS(i + 2, cur);
    }
  }
#undef QALOAD
#undef QBISS

  if (mode == 1) {  // row-major [M][512] bf16, coalesced
#pragma unroll
    for (int nt = 0; nt < 2; ++nt) {
      int col = bn + w * 32 + nt * 16 + lane15;
      float bv = bias0[IPERMC(col)];
#pragma unroll
      for (int mt = 0; mt < 4; ++mt) {
        int row0 = bm + mt * 16 + quad * 4;
#pragma unroll
        for (int r = 0; r < 4; ++r)
          ((us16*)C0)[(size_t)(row0 + r) * 512 + col] = f2bf(acc[mt][nt][r] + bv);
      }
    }
  } else {  // mode 4: fused K (row-major) / V (plane layout), N=1024
#pragma unroll
    for (int nt = 0; nt < 2; ++nt) {
      int col = bn + w * 32 + nt * 16 + lane15;
      if (col < 512) {
        float bv = bias0[IPERMC(col)];
#pragma unroll
        for (int mt = 0; mt < 4; ++mt) {
          int row0 = bm + mt * 16 + quad * 4;
#pragma unroll
          for (int r = 0; r < 4; ++r)
            ((us16*)C0)[(size_t)(row0 + r) * 512 + col] = f2bf(acc[mt][nt][r] + bv);
        }
      } else {
        int cv = col - 512;
        float bv = bias1[cv];
        int plane = (cv & 7) * 64 + (cv >> 3);
#pragma unroll
        for (int mt = 0; mt < 4; ++mt) {
          int row0 = bm + mt * 16 + quad * 4;
          ushort4 pk;
          pk.x = f2bf(acc[mt][nt][0] + bv);
          pk.y = f2bf(acc[mt][nt][1] + bv);
          pk.z = f2bf(acc[mt][nt][2] + bv);
          pk.w = f2bf(acc[mt][nt][3] + bv);
          *(ushort4*)((us16*)C1 + (size_t)plane * M + row0) = pk;
        }
      }
    }
  }
}

// ---------------------------------------------------------------------------
// gemm_qkv: blocks [0,1280) = Q / fused-KV projections (fp32-A reg-staged,
// XCD-swizzled). Blocks [1280,1474) = FFN weight prep riding along (hidden
// under the GEMM span; independent work): r<64 wprep (Wc = W1b@Wm into Wf
// cols 512+PERMC(k)), r<128 W1a strided cast, r<192 W2 cast, r<194 b1p.
// ---------------------------------------------------------------------------
__global__ __launch_bounds__(256) void gemm_qkv(
    const float* __restrict__ dstF, const float* __restrict__ srcF,
    const us16* __restrict__ Wqb, const us16* __restrict__ Wkv,
    const float* __restrict__ bq, const float* __restrict__ bk,
    const float* __restrict__ bv,
    us16* __restrict__ Qh, us16* __restrict__ Kh, us16* __restrict__ Vt,
    const float* __restrict__ W1, const float* __restrict__ Wm,
    const float* __restrict__ W2, const float* __restrict__ b1,
    const float* __restrict__ bm,
    us16* __restrict__ Wf, us16* __restrict__ W2b, float* __restrict__ b1p,
    int Md, int Ms) {
  __shared__ __align__(16) us16 As[2 * 64 * 64];    // 16 KB
  __shared__ __align__(16) us16 Bs[2 * 128 * 64];   // 32 KB
  const int nq = (Md / 64) * 4;
  const int ngemm = nq + (Ms / 64) * 8;  // 1280
  const int blk = blockIdx.x, t = threadIdx.x;

  if (blk >= ngemm) {  // ---- aux: FFN-weight prep ----
    const int r = blk - ngemm;
    if (r < 64) {  // wprep: Wc[n][k] -> Wf[n*1024+512+PERMC(k)]
      us16* Asw = As;
      us16* Bsw = As + 3072;
      const int bx = r & 7, byk = r >> 3;
      const int w = t >> 6, lane = t & 63;
      const int lane15 = lane & 15, quad = lane >> 4;
      const int wm = w >> 1, wn = w & 1;
      const int bn_ = bx * 64, bk = byk * 64;
      floatx4 acc[2][2];
#pragma unroll
      for (int a = 0; a < 2; ++a)
#pragma unroll
        for (int c = 0; c < 2; ++c) acc[a][c] = (floatx4){0.f, 0.f, 0.f, 0.f};
      for (int j0 = 0; j0 < 512; j0 += 32) {
        {
          int n = t >> 2, jj0 = (t & 3) * 8;
          const float* rp = W1 + (size_t)(bn_ + n) * 1024 + 512 + j0 + jj0;
          float4 va = *(const float4*)(rp);
          float4 vb = *(const float4*)(rp + 4);
          ushort4 pa, pb;
          pa.x = f2bf(va.x); pa.y = f2bf(va.y); pa.z = f2bf(va.z); pa.w = f2bf(va.w);
          pb.x = f2bf(vb.x); pb.y = f2bf(vb.y); pb.z = f2bf(vb.z); pb.w = f2bf(vb.w);
          *(ushort4*)(Asw + n * 48 + jj0) = pa;
          *(ushort4*)(Asw + n * 48 + jj0 + 4) = pb;
        }
        {
          int jj = t >> 3, kc0 = (t & 7) * 8;
          const float* rp = Wm + (size_t)(j0 + jj) * 512 + bk + kc0;
          float4 va = *(const float4*)(rp);
          float4 vb = *(const float4*)(rp + 4);
          float vv[8] = {va.x, va.y, va.z, va.w, vb.x, vb.y, vb.z, vb.w};
#pragma unroll
          for (int e = 0; e < 8; ++e) Bsw[(kc0 + e) * 48 + jj] = f2bf(vv[e]);
        }
        __syncthreads();
        short8 a_[2], b_[2];
#pragma unroll
        for (int mt = 0; mt < 2; ++mt)
          a_[mt] = *(const short8*)(Asw + (wm * 32 + mt * 16 + lane15) * 48 + quad * 8);
#pragma unroll
        for (int nt = 0; nt < 2; ++nt)
          b_[nt] = *(const short8*)(Bsw + (wn * 32 + nt * 16 + lane15) * 48 + quad * 8);
#pragma unroll
        for (int mt = 0; mt < 2; ++mt)
#pragma unroll
          for (int nt = 0; nt < 2; ++nt)
            acc[mt][nt] = __builtin_amdgcn_mfma_f32_16x16x32_bf16(
                a_[mt], b_[nt], acc[mt][nt], 0, 0, 0);
        __syncthreads();
      }
#pragma unroll
      for (int mt = 0; mt < 2; ++mt) {
        int n0 = bn_ + wm * 32 + mt * 16 + quad * 4;
#pragma unroll
        for (int nt = 0; nt < 2; ++nt) {
          int k = bk + wn * 32 + nt * 16 + lane15;
          int kp = PERMC(k);
#pragma unroll
          for (int rr = 0; rr < 4; ++rr)
            Wf[(size_t)(n0 + rr) * 1024 + 512 + kp] = f2bf(acc[mt][nt][rr]);
        }
      }
    } else if (r < 128) {  // W1a strided cast: Wf cols 0..511 of 1024 rows
      int idx = r - 64;
#pragma unroll
      for (int e = 0; e < 4; ++e) {
        int i = idx * 4096 + (e * 256 + t) * 4;
        int j = ((i >> 9) * 1024) + (i & 511);
        float4 v = *(const float4*)(W1 + j);
        ushort4 o;
        o.x = f2bf(v.x); o.y = f2bf(v.y); o.z = f2bf(v.z); o.w = f2bf(v.w);
        *(ushort4*)(Wf + j) = o;
      }
    } else if (r < 192) {  // W2 cast
      int idx = r - 128;
#pragma unroll
      for (int e = 0; e < 4; ++e) {
        int i = idx * 4096 + (e * 256 + t) * 4;
        float4 v = *(const float4*)(W2 + i);
        ushort4 o;
        o.x = f2bf(v.x); o.y = f2bf(v.y); o.z = f2bf(v.z); o.w = f2bf(v.w);
        *(ushort4*)(W2b + i) = o;
      }
    } else if (r < 194) {  // b1p = b1 + W1b @ bm
      int n = (r - 192) * 256 + t;
      if (n < 512) {
        const float* rp = W1 + (size_t)n * 1024 + 512;
        float s = 0.f;
        for (int j = 0; j < 512; j += 4) {
          float4 a = *(const float4*)(rp + j);
          float4 c = *(const float4*)(bm + j);
          s += a.x * c.x + a.y * c.y + a.z * c.z + a.w * c.w;
        }
        b1p[n] = b1[n] + s;
      }
    }
    return;
  }

  int i = (blk & 7) * (ngemm >> 3) + (blk >> 3);  // XCD-contiguous (1280%8==0)
  if (i < nq) {
    qkv_body(dstF, Wqb, bq, nullptr, Qh, nullptr, Md, 1, i >> 2, i & 3, As, Bs);
  } else {
    int j = i - nq;
    qkv_body(srcF, Wkv, bk, bv, Kh, Vt, Ms, 4, j >> 3, j & 7, As, Bs);
  }
}

// ---------------------------------------------------------------------------
// gemm_ffn1: FFN1 with mixed A-staging. C = [dst | Ob] @ Wf^T + b1p -> X1
// fp32 + BN1 stats. K = 1024 (nk = 16): chunks 0-7 reg-stage dst fp32
// (8 vm ops), chunks 8-15 gld16 from Ob bf16 (6 vm ops). Counted wait =
// ops(next chunk): vmcnt(8) for i<7, vmcnt(6) for 7<=i<15, vmcnt(0) last.
// ---------------------------------------------------------------------------
__global__ __launch_bounds__(256) void gemm_ffn1(
    const float* __restrict__ dstF, const us16* __restrict__ Ob,
    const us16* __restrict__ Wf, const float* __restrict__ b1p,
    float* __restrict__ X1, float* __restrict__ st1, int M) {
  __shared__ __align__(16) us16 As[2 * 64 * 64];    // 16 KB
  __shared__ __align__(16) us16 Bs[2 * 128 * 64];   // 32 KB
  int b = blockIdx.x;
  int i0 = (b & 7) * ((int)gridDim.x >> 3) + (b >> 3);  // XCD-contig (376%8==0)
  const int bx = i0 >> 2, by = i0 & 3;
  const int t = threadIdx.x, w = t >> 6, lane = t & 63;
  const int lane15 = lane & 15, quad = lane >> 4;
  const int bm = bx * 64, bn = by * 128;
  const int lrow = lane >> 3, sl = lane & 7;
  const int arow = t >> 2, ac4 = (t & 3) * 16, s0 = (t & 3) * 2;

  floatx4 acc[4][2];
#pragma unroll
  for (int a = 0; a < 4; ++a)
#pragma unroll
    for (int c = 0; c < 2; ++c) acc[a][c] = (floatx4){0.f, 0.f, 0.f, 0.f};

#define F1ALOAD(dst, ii)                                                     \
  {                                                                          \
    const float* p_ = dstF + (size_t)(bm + arow) * 512 + ((ii) << 6) + ac4;  \
    dst[0] = *(const float4*)(p_);                                           \
    dst[1] = *(const float4*)(p_ + 4);                                       \
    dst[2] = *(const float4*)(p_ + 8);                                       \
    dst[3] = *(const float4*)(p_ + 12);                                      \
  }
#define F1AGLD(ii, bb)                                                       \
  {                                                                          \
    int ka = ((ii) << 6) - 512;                                              \
    _Pragma("unroll")                                                        \
    for (int p = 0; p < 2; ++p) {                                            \
      int rbase = p * 32 + w * 8;                                            \
      int row = rbase + lrow;                                                \
      int kg = sl ^ SW3(row);                                                \
      gld16(Ob + (size_t)(bm + row) * 512 + ka + kg * 8,                     \
            As + (bb) * 4096 + rbase * 64);                                  \
    }                                                                        \
  }
#define F1BISS(ii, bb)                                                       \
  {                                                                          \
    int k0 = (ii) << 6;                                                      \
    _Pragma("unroll")                                                        \
    for (int p = 0; p < 4; ++p) {                                            \
      int rbase = p * 32 + w * 8;                                            \
      int row = rbase + lrow;                                                \
      int kg = sl ^ SW3(row);                                                \
      gld16(Wf + (size_t)(bn + row) * 1024 + k0 + kg * 8,                    \
            Bs + (bb) * 8192 + rbase * 64);                                  \
    }                                                                        \
  }

  float4 areg[2][4];
  F1ALOAD(areg[0], 0);
  F1BISS(0, 0);
  asm volatile("" ::: "memory");
  F1ALOAD(areg[1], 1);
  F1BISS(1, 1);

#pragma unroll
  for (int i = 0; i < 16; ++i) {
    const int cur = i & 1;
    if (i == 15) {
      asm volatile("s_waitcnt vmcnt(0)" ::: "memory");
    } else if (i < 7) {
      asm volatile("s_waitcnt vmcnt(8)" ::: "memory");
    } else {
      asm volatile("s_waitcnt vmcnt(6)" ::: "memory");
    }
    if (i < 8) {  // cvt fp32 A chunk i -> As[cur]
      __align__(16) us16 vv[16];
#pragma unroll
      for (int q = 0; q < 4; ++q)
#pragma unroll
        for (int j = 0; j < 4; ++j)
          vv[q * 4 + j] = f2bf(((const float*)&areg[cur][q])[j]);
      us16* base = As + cur * 4096 + arow * 64;
      *(short8*)(base + ((s0 ^ SW3(arow)) * 8)) = *(short8*)&vv[0];
      *(short8*)(base + (((s0 + 1) ^ SW3(arow)) * 8)) = *(short8*)&vv[8];
      asm volatile("s_waitcnt lgkmcnt(0)" ::: "memory");
    }
    __builtin_amdgcn_s_barrier();
    asm volatile("" ::: "memory");
#pragma unroll
    for (int kh = 0; kh < 2; ++kh) {
      const int g = kh * 4 + quad;
      short8 a_[4], b_[2];
#pragma unroll
      for (int mt = 0; mt < 4; ++mt) {
        int r = mt * 16 + lane15;
        a_[mt] = *(const short8*)(As + cur * 4096 + r * 64 + (g ^ SW3(r)) * 8);
      }
#pragma unroll
      for (int nt = 0; nt < 2; ++nt) {
        int c = w * 32 + nt * 16 + lane15;
        b_[nt] = *(const short8*)(Bs + cur * 8192 + c * 64 + (g ^ SW3(c)) * 8);
      }
#pragma unroll
      for (int mt = 0; mt < 4; ++mt)
#pragma unroll
        for (int nt = 0; nt < 2; ++nt)
          acc[mt][nt] = __builtin_amdgcn_mfma_f32_16x16x32_bf16(
              a_[mt], b_[nt], acc[mt][nt], 0, 0, 0);
    }
    asm volatile("" ::: "memory");
    __builtin_amdgcn_s_barrier();
    asm volatile("" ::: "memory");
    if (i + 2 < 16) {
      if (i + 2 < 8) {
        F1ALOAD(areg[cur], i + 2);
        F1BISS(i + 2, cur);
      } else {
        F1AGLD(i + 2, cur);
        F1BISS(i + 2, cur);
      }
    }
  }
#undef F1ALOAD
#undef F1AGLD
#undef F1BISS

  // epilogue: fp32 out + BN1 stats
#pragma unroll
  for (int nt = 0; nt < 2; ++nt) {
    int col = bn + w * 32 + nt * 16 + lane15;
    float bv = b1p[col];
    float s = 0.f, qq = 0.f;
#pragma unroll
    for (int mt = 0; mt < 4; ++mt) {
      int row0 = bm + mt * 16 + quad * 4;
#pragma unroll
      for (int r = 0; r < 4; ++r) {
        float val = acc[mt][nt][r] + bv;
        X1[(size_t)(row0 + r) * 512 + col] = val;
        s += val; qq = fmaf(val, val, qq);
      }
    }
    s += __shfl_xor(s, 16); s += __shfl_xor(s, 32);
    qq += __shfl_xor(qq, 16); qq += __shfl_xor(qq, 32);
    if (quad == 0) {
      atomicAdd(&st1[col], s);
      atomicAdd(&st1[512 + col], qq);
    }
  }
}

// ---------------------------------------------------------------------------
// gemm_ffn2bn: FFN2 with BN1+ReLU fused into A-staging (R6-verified).
// ---------------------------------------------------------------------------
__global__ __launch_bounds__(256) void gemm_ffn2bn(
    const float* __restrict__ X1, const us16* __restrict__ W,
    const float* __restrict__ st1, const float* __restrict__ g1,
    const float* __restrict__ be1, const float* __restrict__ b2,
    float* __restrict__ X2, float* __restrict__ st2, int M, float invM) {
  __shared__ __align__(16) us16 As[2 * 64 * 64];    // 16 KB
  __shared__ __align__(16) us16 Bs[2 * 128 * 64];   // 32 KB
  __shared__ float slt[512], tlt[512];              //  4 KB
  int b = blockIdx.x;
  int i0 = (b & 7) * ((int)gridDim.x >> 3) + (b >> 3);  // XCD-contiguous
  const int bx = i0 >> 2, by = i0 & 3;
  const int t = threadIdx.x, w = t >> 6, lane = t & 63;
  const int lane15 = lane & 15, quad = lane >> 4;
  const int bm = bx * 64, bn = by * 128;
  const int lrow = lane >> 3, sl = lane & 7;
  const int arow = t >> 2, ac4 = (t & 3) * 16, s0 = (t & 3) * 2;

  for (int c = t; c < 512; c += 256) {
    float mean = st1[c] * invM;
    float var = fmaf(-mean, mean, st1[512 + c] * invM);
    float inv = rsqrtf(var + 1e-5f) * g1[c];
    slt[c] = inv;
    tlt[c] = be1[c] - mean * inv;
  }
  __syncthreads();

  floatx4 acc[4][2];
#pragma unroll
  for (int a = 0; a < 4; ++a)
#pragma unroll
    for (int c = 0; c < 2; ++c) acc[a][c] = (floatx4){0.f, 0.f, 0.f, 0.f};

#define ALOAD(dst, ii)                                                       \
  {                                                                          \
    const float* p_ = X1 + (size_t)(bm + arow) * 512 + ((ii) << 6) + ac4;    \
    dst[0] = *(const float4*)(p_);                                           \
    dst[1] = *(const float4*)(p_ + 4);                                       \
    dst[2] = *(const float4*)(p_ + 8);                                       \
    dst[3] = *(const float4*)(p_ + 12);                                      \
  }
#define BISSUE(ii, bb)                                                       \
  {                                                                          \
    int k0 = (ii) << 6;                                                      \
    _Pragma("unroll")                                                        \
    for (int p = 0; p < 4; ++p) {                                            \
      int rbase = p * 32 + w * 8;                                            \
      int row = rbase + lrow;                                                \
      int kg = sl ^ SW3(row);                                                \
      gld16(W + (size_t)(bn + row) * 512 + k0 + kg * 8,                      \
            Bs + (bb) * 8192 + rbase * 64);                                  \
    }                                                                        \
  }

  float4 areg[2][4];
  ALOAD(areg[0], 0);
  BISSUE(0, 0);
  asm volatile("" ::: "memory");
  ALOAD(areg[1], 1);
  BISSUE(1, 1);

#pragma unroll
  for (int i = 0; i < 8; ++i) {
    const int cur = i & 1;
    if (i + 1 < 8) {
      asm volatile("s_waitcnt vmcnt(8)" ::: "memory");
    } else {
      asm volatile("s_waitcnt vmcnt(0)" ::: "memory");
    }
    {
      const int k0 = i << 6;
      __align__(16) us16 vv[16];
#pragma unroll
      for (int q = 0; q < 4; ++q) {
#pragma unroll
        for (int j = 0; j < 4; ++j) {
          int c = k0 + ac4 + q * 4 + j;
          float x = ((const float*)&areg[cur][q])[j];
          float y = fmaxf(fmaf(x, slt[c], tlt[c]), 0.f);
          vv[q * 4 + j] = f2bf(y);
        }
      }
      us16* base = As + cur * 4096 + arow * 64;
      *(short8*)(base + ((s0 ^ SW3(arow)) * 8)) = *(short8*)&vv[0];
      *(short8*)(base + (((s0 + 1) ^ SW3(arow)) * 8)) = *(short8*)&vv[8];
    }
    asm volatile("s_waitcnt lgkmcnt(0)" ::: "memory");
    __builtin_amdgcn_s_barrier();
    asm volatile("" ::: "memory");
#pragma unroll
    for (int kh = 0; kh < 2; ++kh) {
      const int g = kh * 4 + quad;
      short8 a_[4], b_[2];
#pragma unroll
      for (int mt = 0; mt < 4; ++mt) {
        int r = mt * 16 + lane15;
        a_[mt] = *(const short8*)(As + cur * 4096 + r * 64 + (g ^ SW3(r)) * 8);
      }
#pragma unroll
      for (int nt = 0; nt < 2; ++nt) {
        int c = w * 32 + nt * 16 + lane15;
        b_[nt] = *(const short8*)(Bs + cur * 8192 + c * 64 + (g ^ SW3(c)) * 8);
      }
#pragma unroll
      for (int mt = 0; mt < 4; ++mt)
#pragma unroll
        for (int nt = 0; nt < 2; ++nt)
          acc[mt][nt] = __builtin_amdgcn_mfma_f32_16x16x32_bf16(
              a_[mt], b_[nt], acc[mt][nt], 0, 0, 0);
    }
    asm volatile("" ::: "memory");
    __builtin_amdgcn_s_barrier();
    asm volatile("" ::: "memory");
    if (i + 2 < 8) {
      ALOAD(areg[cur], i + 2);
      BISSUE(i + 2, cur);
    }
  }
#undef ALOAD
#undef BISSUE

#pragma unroll
  for (int nt = 0; nt < 2; ++nt) {
    int col = bn + w * 32 + nt * 16 + lane15;
    float bv = b2[col];
    float s = 0.f, qq = 0.f;
#pragma unroll
    for (int mt = 0; mt < 4; ++mt) {
      int row0 = bm + mt * 16 + quad * 4;
#pragma unroll
      for (int r = 0; r < 4; ++r) {
        float val = acc[mt][nt][r] + bv;
        X2[(size_t)(row0 + r) * 512 + col] = val;
        s += val; qq = fmaf(val, val, qq);
      }
    }
    s += __shfl_xor(s, 16); s += __shfl_xor(s, 32);
    qq += __shfl_xor(qq, 16); qq += __shfl_xor(qq, 32);
    if (quad == 0) {
      atomicAdd(&st2[col], s);
      atomicAdd(&st2[512 + col], qq);
    }
  }
}

// ---------------------------------------------------------------------------
// attn_v6 (R6-verified, unchanged): 4 waves x 16 dst rows of one (b,h).
// ---------------------------------------------------------------------------
__global__ __launch_bounds__(256) void attn_v6(
    const us16* __restrict__ Qh, const us16* __restrict__ Kh,
    const us16* __restrict__ Vt, const int* __restrict__ dlens,
    const int* __restrict__ slens, us16* __restrict__ O,
    int Md, int Ms) {
  const int b = blockIdx.x, h = blockIdx.y, tile = blockIdx.z;
  int doff = 0, soff = 0;
  for (int i = 0; i < NBATCH; ++i)
    if (i < b) { doff += dlens[i]; soff += slens[i]; }
  const int dlen = dlens[b], slen = slens[b];
  if (tile * 64 >= dlen) return;

  __shared__ __align__(16) us16 Ks[2 * 64 * 64];   // 16 KB
  __shared__ __align__(16) us16 Vts[2 * 64 * 64];  // 16 KB
  __shared__ __align__(16) us16 Pw[4][16 * 72];

  const int t = threadIdx.x, wv = t >> 6, lane = t & 63;
  const int lane15 = lane & 15, quad = lane >> 4;
  const int i0w = tile * 64 + wv * 16;
  const bool active = i0w < dlen;  // dlen % 16 == 0

  const us16* Qp = Qh + ((size_t)(doff + (active ? i0w : 0))) * 512 + h * 64;
  const us16* Kp = Kh + ((size_t)soff) * 512 + h * 64;
  const us16* Vtp = Vt + ((size_t)h * 64) * Ms + soff;

  short8 af0 = *(const short8*)(Qp + (size_t)lane15 * 512 + quad * 8);
  short8 af1 = *(const short8*)(Qp + (size_t)lane15 * 512 + 32 + quad * 8);

  floatx4 oa[4];
#pragma unroll
  for (int nt = 0; nt < 4; ++nt) oa[nt] = (floatx4){0.f, 0.f, 0.f, 0.f};
  float m_r[4] = {-3.0e38f, -3.0e38f, -3.0e38f, -3.0e38f};
  float l_r[4] = {0.f, 0.f, 0.f, 0.f};

  const int nc = (slen + 63) >> 6;

#define KVST(c, bu)                                                       \
  {                                                                       \
    int jb = (c) << 6;                                                    \
    _Pragma("unroll")                                                     \
    for (int p = 0; p < 2; ++p) {                                         \
      int row = wv * 16 + p * 8 + (lane >> 3);                            \
      int slt = lane & 7;                                                 \
      int kg = slt ^ SW3(row);                                            \
      gld16(Kp + (size_t)(jb + row) * 512 + kg * 8,                       \
            Ks + (bu) * 4096 + (wv * 16 + p * 8) * 64);                   \
      gld16(Vtp + (size_t)row * Ms + jb + kg * 8,                         \
            Vts + (bu) * 4096 + (wv * 16 + p * 8) * 64);                  \
    }                                                                     \
  }

  KVST(0, 0);
  if (nc > 1) KVST(1, 1);
  for (int c = 0; c < nc; ++c) {
    const int cur = c & 1;
    if (c + 1 < nc) {
      asm volatile("s_waitcnt vmcnt(4)" ::: "memory");
    } else {
      asm volatile("s_waitcnt vmcnt(0)" ::: "memory");
    }
    __builtin_amdgcn_s_barrier();
    asm volatile("" ::: "memory");

    if (active) {
      const int j0 = c << 6;
      floatx4 s[4];
#pragma unroll
      for (int jt = 0; jt < 4; ++jt) {
        int j = jt * 16 + lane15;
        short8 b0 = *(const short8*)(Ks + cur * 4096 + j * 64 + ((quad ^ SW3(j)) * 8));
        short8 b1 = *(const short8*)(Ks + cur * 4096 + j * 64 + (((4 + quad) ^ SW3(j)) * 8));
        floatx4 a = (floatx4){0.f, 0.f, 0.f, 0.f};
        a = __builtin_amdgcn_mfma_f32_16x16x32_bf16(af0, b0, a, 0, 0, 0);
        a = __builtin_amdgcn_mfma_f32_16x16x32_bf16(af1, b1, a, 0, 0, 0);
        s[jt] = a;
      }
      float mx[4] = {-3.0e38f, -3.0e38f, -3.0e38f, -3.0e38f};
#pragma unroll
      for (int jt = 0; jt < 4; ++jt) {
        bool valid = (j0 + jt * 16 + lane15) < slen;
#pragma unroll
        for (int r = 0; r < 4; ++r) {
          float v = valid ? s[jt][r] * 0.125f : -3.0e38f;
          s[jt][r] = v;
          mx[r] = fmaxf(mx[r], v);
        }
      }
#pragma unroll
      for (int r = 0; r < 4; ++r) {
        mx[r] = fmaxf(mx[r], __shfl_xor(mx[r], 1));
        mx[r] = fmaxf(mx[r], __shfl_xor(mx[r], 2));
        mx[r] = fmaxf(mx[r], __shfl_xor(mx[r], 4));
        mx[r] = fmaxf(mx[r], __shfl_xor(mx[r], 8));
      }
      float al[4], sum[4];
#pragma unroll
      for (int r = 0; r < 4; ++r) {
        float mn = fmaxf(m_r[r], mx[r]);
        al[r] = __expf(m_r[r] - mn);
        m_r[r] = mn;
        sum[r] = 0.f;
      }
#pragma unroll
      for (int jt = 0; jt < 4; ++jt)
#pragma unroll
        for (int r = 0; r < 4; ++r) {
          float e = __expf(s[jt][r] - m_r[r]);
          sum[r] += e;
          Pw[wv][(quad * 4 + r) * 72 + jt * 16 + lane15] = f2bf(e);
        }
#pragma unroll
      for (int r = 0; r < 4; ++r) {
        sum[r] += __shfl_xor(sum[r], 1);
        sum[r] += __shfl_xor(sum[r], 2);
        sum[r] += __shfl_xor(sum[r], 4);
        sum[r] += __shfl_xor(sum[r], 8);
        l_r[r] = l_r[r] * al[r] + sum[r];
      }
#pragma unroll
      for (int nt = 0; nt < 4; ++nt)
#pragma unroll
        for (int r = 0; r < 4; ++r) oa[nt][r] *= al[r];
      short8 pa0 = *(const short8*)(&Pw[wv][lane15 * 72 + quad * 8]);
      short8 pa1 = *(const short8*)(&Pw[wv][lane15 * 72 + 32 + quad * 8]);
#pragma unroll
      for (int nt = 0; nt < 4; ++nt) {
        int d = nt * 16 + lane15;
        short8 v0 = *(const short8*)(Vts + cur * 4096 + d * 64 + ((quad ^ SW3(d)) * 8));
        short8 v1 = *(const short8*)(Vts + cur * 4096 + d * 64 + (((4 + quad) ^ SW3(d)) * 8));
        oa[nt] = __builtin_amdgcn_mfma_f32_16x16x32_bf16(pa0, v0, oa[nt], 0, 0, 0);
        oa[nt] = __builtin_amdgcn_mfma_f32_16x16x32_bf16(pa1, v1, oa[nt], 0, 0, 0);
      }
    }

    asm volatile("" ::: "memory");
    __builtin_amdgcn_s_barrier();
    asm volatile("" ::: "memory");
    if (c + 2 < nc) KVST(c + 2, cur);
  }
#undef KVST

  if (active) {
    float linv[4];
#pragma unroll
    for (int r = 0; r < 4; ++r) linv[r] = 1.f / l_r[r];
#pragma unroll
    for (int r = 0; r < 4; ++r) {
      int i = quad * 4 + r;
      us16* orow = O + (size_t)(doff + i0w + i) * H_DIM + h * 64;
#pragma unroll
      for (int nt = 0; nt < 4; ++nt) {
        int d = nt * 16 + lane15;
        orow[d] = f2bf(oa[nt][r] * linv[r]);
      }
    }
  }
}

// ---------------------------------------------------------------------------
// bn2_apply: BN2 + residual -> fp32 out, float4-vectorized, grid 2048 (G11).
// ---------------------------------------------------------------------------
__global__ __launch_bounds__(256) void bn2_apply(
    const float* __restrict__ X, const float* __restrict__ stats,
    const float* __restrict__ g, const float* __restrict__ be,
    const float* __restrict__ resid, float* __restrict__ Y,
    int M, float invM) {
  const size_t total4 = (size_t)M * (H_DIM / 4);
  for (size_t i = (size_t)blockIdx.x * 256 + threadIdx.x; i < total4;
       i += (size_t)gridDim.x * 256) {
    int c = (int)((i * 4) & (H_DIM - 1));
    float4 x = ((const float4*)X)[i];
    float4 rr = ((const float4*)resid)[i];
    float4 o;
#pragma unroll
    for (int j = 0; j < 4; ++j) {
      int cc = c + j;
      float mean = stats[cc] * invM;
      float var = fmaf(-mean, mean, stats[H_DIM + cc] * invM);
      float inv = rsqrtf(var + 1e-5f) * g[cc];
      float xv = ((const float*)&x)[j];
      ((float*)&o)[j] = (xv - mean) * inv + be[cc] + ((const float*)&rr)[j];
    }
    ((float4*)Y)[i] = o;
  }
}

// ---------------------------------------------------------------------------
extern "C" void kernel_launch(void* const* d_in, const int* in_sizes, int n_in,
                              void* d_out, int out_size, void* d_ws, size_t ws_size,
                              hipStream_t stream) {
  const float* src_h = (const float*)d_in[0];
  const float* dst_h = (const float*)d_in[1];
  const int* s_lens  = (const int*)d_in[2];
  const int* d_lens  = (const int*)d_in[3];
  const float* Wq = (const float*)d_in[4];  const float* bq = (const float*)d_in[5];
  const float* Wk = (const float*)d_in[6];  const float* bk = (const float*)d_in[7];
  const float* Wv = (const float*)d_in[8];  const float* bv = (const float*)d_in[9];
  const float* Wm = (const float*)d_in[10]; const float* bm = (const float*)d_in[11];
  const float* W1 = (const float*)d_in[12]; const float* b1 = (const float*)d_in[13];
  const float* g1 = (const float*)d_in[14]; const float* be1 = (const float*)d_in[15];
  const float* W2 = (const float*)d_in[16]; const float* b2 = (const float*)d_in[17];
  const float* g2 = (const float*)d_in[18]; const float* be2 = (const float*)d_in[19];

  const int total_src = in_sizes[0] / H_DIM;  // 7232 = 113*64
  const int total_dst = in_sizes[1] / H_DIM;  // 6016 = 94*64

  // ---- workspace layout (byte offsets); peak ~30.3 MB ----
  char* ws = (char*)d_ws;
  us16* wbf  = (us16*)(ws + 0);              // 3,145,728 weights bf16
  float* b1p = (float*)(ws + 3145728);       // 2,048
  float* st  = (float*)(ws + 3147776);       // 8,192
  us16* Qh   = (us16*)(ws + 3155968);        // 6,160,384
  us16* Kh   = (us16*)(ws + 9316352);        // 7,405,568
  us16* Vt   = (us16*)(ws + 16721920);       // 7,405,568
  us16* Ob   = (us16*)(ws + 24127488);       // 6,160,384 (ends 30,287,872)
  float* X1  = (float*)(ws + 3155968);       // 12,320,768 (aliases Qh+Kh, dead)
  float* X2  = (float*)(ws + 16721920);      // 12,320,768 (aliases Vt+Ob head;
                                             //  Ob dead after FFN1 reads)
  float* st1 = st, *st2 = st + 1024;

  us16* Wqb = wbf;                 // 262144 elems (rows permuted head-major)
  us16* Wkv = wbf + 262144;        // 524288 (Wk rows permuted, then Wv rows)
  us16* Wf  = wbf + 786432;        // 524288 ([W1a | Wc-perm] rows of 1024)
  us16* W2b = wbf + 1310720;       // 262144

  const int mbd = total_dst / 64;  // 94
  const int mbs = total_src / 64;  // 113
  const int ngemm = mbd * 4 + mbs * 8;  // 1280
  const dim3 blk256(256);
  const float invM = 1.f / (float)total_dst;

  // 1: QKV weight casts + stat zero (small: 3 MB)
  prep0<<<dim3(768), blk256, 0, stream>>>(Wq, Wk, Wv, Wqb, Wkv, st);

  // 2: Q + fused K/V projections (fp32-A reg-staged) + FFN-weight prep
  //    riding as 194 extra blocks (hidden under the GEMM span)
  gemm_qkv<<<dim3(ngemm + 194), blk256, 0, stream>>>(
      dst_h, src_h, Wqb, Wkv, bq, bk, bv, Qh, Kh, Vt,
      W1, Wm, W2, b1, bm, Wf, W2b, b1p, total_dst, total_src);

  // 3: attention -> Ob (bf16 [M,512] head-major)
  attn_v6<<<dim3(NBATCH, N_HEADS, 8), blk256, 0, stream>>>(
      Qh, Kh, Vt, d_lens, s_lens, Ob, total_dst, total_src);

  // 4: FFN1 mixed-A: [dst fp32 | Ob bf16] @ Wf^T + b1p -> X1 + BN1 stats
  gemm_ffn1<<<dim3(mbd * 4), blk256, 0, stream>>>(
      dst_h, Ob, Wf, b1p, X1, st1, total_dst);

  // 5: FFN2 with fused BN1+ReLU on A: BN1(X1) @ W2b^T + b2 -> X2 + BN2 stats
  gemm_ffn2bn<<<dim3(mbd * 4), blk256, 0, stream>>>(
      X1, W2b, st1, g1, be1, b2, X2, st2, total_dst, invM);

  // 6: BN2 + residual -> d_out (fp32, float4, 2048 blocks)
  bn2_apply<<<dim3(2048), blk256, 0, stream>>>(
      X2, st2, g2, be2, dst_h, (float*)d_out, total_dst, invM);
}

// Round 9
// 217.268 us; speedup vs baseline: 1.0145x; 1.0145x over previous
//
#include <hip/hip_runtime.h>
#include <hip/hip_bf16.h>

#define H_DIM 512
#define N_HEADS 8
#define HEAD_DIM 64
#define NBATCH 16

typedef __attribute__((ext_vector_type(8))) short short8;   // 8 bf16 (4 VGPRs)
typedef __attribute__((ext_vector_type(4))) float floatx4;  // MFMA acc

typedef unsigned short us16;

// 3-bit row swizzle for XOR'd LDS slots (structurally conflict-free b128)
#define SW3(r) ((((r) >> 1) & 3) | (((r) & 1) << 2))

// head-major channel permutation: c (=d*8+h) -> c' (=h*64+d)
#define PERMC(c) ((((c) & 7) << 6) | ((c) >> 3))
// inverse: c' -> c
#define IPERMC(cp) ((((cp) & 63) << 3) | ((cp) >> 6))

__device__ inline unsigned short f2bf(float f) {
  unsigned int u = __float_as_uint(f);
  unsigned int r = (u + 0x7fffu + ((u >> 16) & 1u)) >> 16;  // RNE
  return (unsigned short)r;
}

// async global->LDS, 16B/lane; lds dest = wave-uniform base + lane*16
__device__ inline void gld16(const us16* g, us16* l) {
  __builtin_amdgcn_global_load_lds(
      (const __attribute__((address_space(1))) void*)g,
      (__attribute__((address_space(3))) void*)l, 16, 0, 0);
}

// ---------------------------------------------------------------------------
// prep0: QKV weight casts (Wq/Wk row-permuted head-major, Wv straight) +
// BN-stat zero + ragged batch-offset prefix table (16 adds by one thread;
// saves every attn block a serial 16-load loop at startup). 768 blocks.
// ---------------------------------------------------------------------------
__global__ __launch_bounds__(256) void prep0(
    const float* __restrict__ Wq, const float* __restrict__ Wk,
    const float* __restrict__ Wv, const int* __restrict__ dlens,
    const int* __restrict__ slens,
    us16* __restrict__ Wqb, us16* __restrict__ Wkv, float* __restrict__ st,
    int* __restrict__ offs) {
  const int blk = blockIdx.x, t = threadIdx.x;
  if (blk == 0) {
    float4 z = make_float4(0.f, 0.f, 0.f, 0.f);
    ((float4*)st)[t] = z;
    ((float4*)st)[t + 256] = z;
    if (t == 0) {
      int d = 0, s = 0;
      for (int i = 0; i < NBATCH; ++i) {
        offs[i] = d; offs[16 + i] = s;
        d += dlens[i]; s += slens[i];
      }
    }
  }
  const int rg = blk >> 8;
  const float* sp = (rg == 0) ? Wq : (rg == 1) ? Wk : Wv;
  us16* dp = (rg == 0) ? Wqb : (rg == 1) ? Wkv : (Wkv + 262144);
  const int i = (((blk & 255) << 8) + t) << 2;  // 0..262140
  float4 v = *(const float4*)(sp + i);
  ushort4 o;
  o.x = f2bf(v.x); o.y = f2bf(v.y); o.z = f2bf(v.z); o.w = f2bf(v.w);
  int jd = (rg < 2) ? ((PERMC(i >> 9) << 9) + (i & 511)) : i;
  *(ushort4*)(dp + jd) = o;
}

// ---------------------------------------------------------------------------
// 64x128 GEMM body, A reg-staged from FP32, B via gld16 (R7-verified).
// K=512 (nk=8). Per chunk 8 vm ops; counted vmcnt(8). 48 KB LDS.
// modes: 1 bf16 row-major [M][512] head-major cols; 4 fused K/V.
// ---------------------------------------------------------------------------
__device__ inline void qkv_body(
    const float* __restrict__ actF, const us16* __restrict__ W,
    const float* __restrict__ bias0, const float* __restrict__ bias1,
    void* __restrict__ C0, void* __restrict__ C1,
    int M, int mode, int bx, int by, us16* As, us16* Bs) {
  const int t = threadIdx.x, w = t >> 6, lane = t & 63;
  const int lane15 = lane & 15, quad = lane >> 4;
  const int bm = bx * 64, bn = by * 128;
  const int lrow = lane >> 3, sl = lane & 7;
  const int arow = t >> 2, ac4 = (t & 3) * 16, s0 = (t & 3) * 2;

  floatx4 acc[4][2];
#pragma unroll
  for (int a = 0; a < 4; ++a)
#pragma unroll
    for (int c = 0; c < 2; ++c) acc[a][c] = (floatx4){0.f, 0.f, 0.f, 0.f};

#define QALOAD(dst, ii)                                                      \
  {                                                                          \
    const float* p_ = actF + (size_t)(bm + arow) * 512 + ((ii) << 6) + ac4;  \
    dst[0] = *(const float4*)(p_);                                           \
    dst[1] = *(const float4*)(p_ + 4);                                       \
    dst[2] = *(const float4*)(p_ + 8);                                       \
    dst[3] = *(const float4*)(p_ + 12);                                      \
  }
#define QBISS(ii, bb)                                                        \
  {                                                                          \
    int k0 = (ii) << 6;                                                      \
    _Pragma("unroll")                                                        \
    for (int p = 0; p < 4; ++p) {                                            \
      int rbase = p * 32 + w * 8;                                            \
      int row = rbase + lrow;                                                \
      int kg = sl ^ SW3(row);                                                \
      gld16(W + (size_t)(bn + row) * 512 + k0 + kg * 8,                      \
            Bs + (bb) * 8192 + rbase * 64);                                  \
    }                                                                        \
  }

  float4 areg[2][4];
  QALOAD(areg[0], 0);
  QBISS(0, 0);
  asm volatile("" ::: "memory");
  QALOAD(areg[1], 1);
  QBISS(1, 1);

#pragma unroll
  for (int i = 0; i < 8; ++i) {
    const int cur = i & 1;
    if (i < 7) {
      asm volatile("s_waitcnt vmcnt(8)" ::: "memory");
    } else {
      asm volatile("s_waitcnt vmcnt(0)" ::: "memory");
    }
    {  // cvt A chunk i -> As[cur]
      __align__(16) us16 vv[16];
#pragma unroll
      for (int q = 0; q < 4; ++q)
#pragma unroll
        for (int j = 0; j < 4; ++j)
          vv[q * 4 + j] = f2bf(((const float*)&areg[cur][q])[j]);
      us16* base = As + cur * 4096 + arow * 64;
      *(short8*)(base + ((s0 ^ SW3(arow)) * 8)) = *(short8*)&vv[0];
      *(short8*)(base + (((s0 + 1) ^ SW3(arow)) * 8)) = *(short8*)&vv[8];
    }
    asm volatile("s_waitcnt lgkmcnt(0)" ::: "memory");
    __builtin_amdgcn_s_barrier();
    asm volatile("" ::: "memory");
#pragma unroll
    for (int kh = 0; kh < 2; ++kh) {
      const int g = kh * 4 + quad;
      short8 a_[4], b_[2];
#pragma unroll
      for (int mt = 0; mt < 4; ++mt) {
        int r = mt * 16 + lane15;
        a_[mt] = *(const short8*)(As + cur * 4096 + r * 64 + (g ^ SW3(r)) * 8);
      }
#pragma unroll
      for (int nt = 0; nt < 2; ++nt) {
        int c = w * 32 + nt * 16 + lane15;
        b_[nt] = *(const short8*)(Bs + cur * 8192 + c * 64 + (g ^ SW3(c)) * 8);
      }
#pragma unroll
      for (int mt = 0; mt < 4; ++mt)
#pragma unroll
        for (int nt = 0; nt < 2; ++nt)
          acc[mt][nt] = __builtin_amdgcn_mfma_f32_16x16x32_bf16(
              a_[mt], b_[nt], acc[mt][nt], 0, 0, 0);
    }
    asm volatile("" ::: "memory");
    __builtin_amdgcn_s_barrier();
    asm volatile("" ::: "memory");
    if (i + 2 < 8) {
      QALOAD(areg[cur], i + 2);
      QBISS(i + 2, cur);
    }
  }
#undef QALOAD
#undef QBISS

  if (mode == 1) {  // row-major [M][512] bf16, coalesced
#pragma unroll
    for (int nt = 0; nt < 2; ++nt) {
      int col = bn + w * 32 + nt * 16 + lane15;
      float bv = bias0[IPERMC(col)];
#pragma unroll
      for (int mt = 0; mt < 4; ++mt) {
        int row0 = bm + mt * 16 + quad * 4;
#pragma unroll
        for (int r = 0; r < 4; ++r)
          ((us16*)C0)[(size_t)(row0 + r) * 512 + col] = f2bf(acc[mt][nt][r] + bv);
      }
    }
  } else {  // mode 4: fused K (row-major) / V (plane layout), N=1024
#pragma unroll
    for (int nt = 0; nt < 2; ++nt) {
      int col = bn + w * 32 + nt * 16 + lane15;
      if (col < 512) {
        float bv = bias0[IPERMC(col)];
#pragma unroll
        for (int mt = 0; mt < 4; ++mt) {
          int row0 = bm + mt * 16 + quad * 4;
#pragma unroll
          for (int r = 0; r < 4; ++r)
            ((us16*)C0)[(size_t)(row0 + r) * 512 + col] = f2bf(acc[mt][nt][r] + bv);
        }
      } else {
        int cv = col - 512;
        float bv = bias1[cv];
        int plane = (cv & 7) * 64 + (cv >> 3);
#pragma unroll
        for (int mt = 0; mt < 4; ++mt) {
          int row0 = bm + mt * 16 + quad * 4;
          ushort4 pk;
          pk.x = f2bf(acc[mt][nt][0] + bv);
          pk.y = f2bf(acc[mt][nt][1] + bv);
          pk.z = f2bf(acc[mt][nt][2] + bv);
          pk.w = f2bf(acc[mt][nt][3] + bv);
          *(ushort4*)((us16*)C1 + (size_t)plane * M + row0) = pk;
        }
      }
    }
  }
}

// ---------------------------------------------------------------------------
// gemm_qkv: blocks [0,1280) = Q / fused-KV projections. Blocks [1280,1474)
// = FFN weight prep riding along (independent).
// ---------------------------------------------------------------------------
__global__ __launch_bounds__(256) void gemm_qkv(
    const float* __restrict__ dstF, const float* __restrict__ srcF,
    const us16* __restrict__ Wqb, const us16* __restrict__ Wkv,
    const float* __restrict__ bq, const float* __restrict__ bk,
    const float* __restrict__ bv,
    us16* __restrict__ Qh, us16* __restrict__ Kh, us16* __restrict__ Vt,
    const float* __restrict__ W1, const float* __restrict__ Wm,
    const float* __restrict__ W2, const float* __restrict__ b1,
    const float* __restrict__ bm,
    us16* __restrict__ Wf, us16* __restrict__ W2b, float* __restrict__ b1p,
    int Md, int Ms) {
  __shared__ __align__(16) us16 As[2 * 64 * 64];    // 16 KB
  __shared__ __align__(16) us16 Bs[2 * 128 * 64];   // 32 KB
  const int nq = (Md / 64) * 4;
  const int ngemm = nq + (Ms / 64) * 8;  // 1280
  const int blk = blockIdx.x, t = threadIdx.x;

  if (blk >= ngemm) {  // ---- aux: FFN-weight prep ----
    const int r = blk - ngemm;
    if (r < 64) {  // wprep: Wc[n][k] -> Wf[n*1024+512+PERMC(k)]
      us16* Asw = As;
      us16* Bsw = As + 3072;
      const int bx = r & 7, byk = r >> 3;
      const int w = t >> 6, lane = t & 63;
      const int lane15 = lane & 15, quad = lane >> 4;
      const int wm = w >> 1, wn = w & 1;
      const int bn_ = bx * 64, bk = byk * 64;
      floatx4 acc[2][2];
#pragma unroll
      for (int a = 0; a < 2; ++a)
#pragma unroll
        for (int c = 0; c < 2; ++c) acc[a][c] = (floatx4){0.f, 0.f, 0.f, 0.f};
      for (int j0 = 0; j0 < 512; j0 += 32) {
        {
          int n = t >> 2, jj0 = (t & 3) * 8;
          const float* rp = W1 + (size_t)(bn_ + n) * 1024 + 512 + j0 + jj0;
          float4 va = *(const float4*)(rp);
          float4 vb = *(const float4*)(rp + 4);
          ushort4 pa, pb;
          pa.x = f2bf(va.x); pa.y = f2bf(va.y); pa.z = f2bf(va.z); pa.w = f2bf(va.w);
          pb.x = f2bf(vb.x); pb.y = f2bf(vb.y); pb.z = f2bf(vb.z); pb.w = f2bf(vb.w);
          *(ushort4*)(Asw + n * 48 + jj0) = pa;
          *(ushort4*)(Asw + n * 48 + jj0 + 4) = pb;
        }
        {
          int jj = t >> 3, kc0 = (t & 7) * 8;
          const float* rp = Wm + (size_t)(j0 + jj) * 512 + bk + kc0;
          float4 va = *(const float4*)(rp);
          float4 vb = *(const float4*)(rp + 4);
          float vv[8] = {va.x, va.y, va.z, va.w, vb.x, vb.y, vb.z, vb.w};
#pragma unroll
          for (int e = 0; e < 8; ++e) Bsw[(kc0 + e) * 48 + jj] = f2bf(vv[e]);
        }
        __syncthreads();
        short8 a_[2], b_[2];
#pragma unroll
        for (int mt = 0; mt < 2; ++mt)
          a_[mt] = *(const short8*)(Asw + (wm * 32 + mt * 16 + lane15) * 48 + quad * 8);
#pragma unroll
        for (int nt = 0; nt < 2; ++nt)
          b_[nt] = *(const short8*)(Bsw + (wn * 32 + nt * 16 + lane15) * 48 + quad * 8);
#pragma unroll
        for (int mt = 0; mt < 2; ++mt)
#pragma unroll
          for (int nt = 0; nt < 2; ++nt)
            acc[mt][nt] = __builtin_amdgcn_mfma_f32_16x16x32_bf16(
                a_[mt], b_[nt], acc[mt][nt], 0, 0, 0);
        __syncthreads();
      }
#pragma unroll
      for (int mt = 0; mt < 2; ++mt) {
        int n0 = bn_ + wm * 32 + mt * 16 + quad * 4;
#pragma unroll
        for (int nt = 0; nt < 2; ++nt) {
          int k = bk + wn * 32 + nt * 16 + lane15;
          int kp = PERMC(k);
#pragma unroll
          for (int rr = 0; rr < 4; ++rr)
            Wf[(size_t)(n0 + rr) * 1024 + 512 + kp] = f2bf(acc[mt][nt][rr]);
        }
      }
    } else if (r < 128) {  // W1a strided cast: Wf cols 0..511 of 1024 rows
      int idx = r - 64;
#pragma unroll
      for (int e = 0; e < 4; ++e) {
        int i = idx * 4096 + (e * 256 + t) * 4;
        int j = ((i >> 9) * 1024) + (i & 511);
        float4 v = *(const float4*)(W1 + j);
        ushort4 o;
        o.x = f2bf(v.x); o.y = f2bf(v.y); o.z = f2bf(v.z); o.w = f2bf(v.w);
        *(ushort4*)(Wf + j) = o;
      }
    } else if (r < 192) {  // W2 cast
      int idx = r - 128;
#pragma unroll
      for (int e = 0; e < 4; ++e) {
        int i = idx * 4096 + (e * 256 + t) * 4;
        float4 v = *(const float4*)(W2 + i);
        ushort4 o;
        o.x = f2bf(v.x); o.y = f2bf(v.y); o.z = f2bf(v.z); o.w = f2bf(v.w);
        *(ushort4*)(W2b + i) = o;
      }
    } else if (r < 194) {  // b1p = b1 + W1b @ bm
      int n = (r - 192) * 256 + t;
      if (n < 512) {
        const float* rp = W1 + (size_t)n * 1024 + 512;
        float s = 0.f;
        for (int j = 0; j < 512; j += 4) {
          float4 a = *(const float4*)(rp + j);
          float4 c = *(const float4*)(bm + j);
          s += a.x * c.x + a.y * c.y + a.z * c.z + a.w * c.w;
        }
        b1p[n] = b1[n] + s;
      }
    }
    return;
  }

  int i = (blk & 7) * (ngemm >> 3) + (blk >> 3);  // XCD-contiguous (1280%8==0)
  if (i < nq) {
    qkv_body(dstF, Wqb, bq, nullptr, Qh, nullptr, Md, 1, i >> 2, i & 3, As, Bs);
  } else {
    int j = i - nq;
    qkv_body(srcF, Wkv, bk, bv, Kh, Vt, Ms, 4, j >> 3, j & 7, As, Bs);
  }
}

// ---------------------------------------------------------------------------
// gemm_ffn1 (R7-verified, 64-row tiles, grid 376): FFN1 mixed A-staging.
// C = [dst | Ob] @ Wf^T + b1p -> X1 fp32 + BN1 stats. K = 1024 (nk = 16):
// chunks 0-7 reg-stage dst fp32 (8 vm ops), chunks 8-15 gld16 from Ob
// (6 vm ops). Wait = ops(next chunk): 8 / 6 / 0.
// ---------------------------------------------------------------------------
__global__ __launch_bounds__(256) void gemm_ffn1(
    const float* __restrict__ dstF, const us16* __restrict__ Ob,
    const us16* __restrict__ Wf, const float* __restrict__ b1p,
    float* __restrict__ X1, float* __restrict__ st1, int M) {
  __shared__ __align__(16) us16 As[2 * 64 * 64];    // 16 KB
  __shared__ __align__(16) us16 Bs[2 * 128 * 64];   // 32 KB
  int b = blockIdx.x;
  int i0 = (b & 7) * ((int)gridDim.x >> 3) + (b >> 3);  // XCD-contig (376%8==0)
  const int bx = i0 >> 2, by = i0 & 3;
  const int t = threadIdx.x, w = t >> 6, lane = t & 63;
  const int lane15 = lane & 15, quad = lane >> 4;
  const int bm = bx * 64, bn = by * 128;
  const int lrow = lane >> 3, sl = lane & 7;
  const int arow = t >> 2, ac4 = (t & 3) * 16, s0 = (t & 3) * 2;

  floatx4 acc[4][2];
#pragma unroll
  for (int a = 0; a < 4; ++a)
#pragma unroll
    for (int c = 0; c < 2; ++c) acc[a][c] = (floatx4){0.f, 0.f, 0.f, 0.f};

#define F1ALOAD(dst, ii)                                                     \
  {                                                                          \
    const float* p_ = dstF + (size_t)(bm + arow) * 512 + ((ii) << 6) + ac4;  \
    dst[0] = *(const float4*)(p_);                                           \
    dst[1] = *(const float4*)(p_ + 4);                                       \
    dst[2] = *(const float4*)(p_ + 8);                                       \
    dst[3] = *(const float4*)(p_ + 12);                                      \
  }
#define F1AGLD(ii, bb)                                                       \
  {                                                                          \
    int ka = ((ii) << 6) - 512;                                              \
    _Pragma("unroll")                                                        \
    for (int p = 0; p < 2; ++p) {                                            \
      int rbase = p * 32 + w * 8;                                            \
      int row = rbase + lrow;                                                \
      int kg = sl ^ SW3(row);                                                \
      gld16(Ob + (size_t)(bm + row) * 512 + ka + kg * 8,                     \
            As + (bb) * 4096 + rbase * 64);                                  \
    }                                                                        \
  }
#define F1BISS(ii, bb)                                                       \
  {                                                                          \
    int k0 = (ii) << 6;                                                      \
    _Pragma("unroll")                                                        \
    for (int p = 0; p < 4; ++p) {                                            \
      int rbase = p * 32 + w * 8;                                            \
      int row = rbase + lrow;                                                \
      int kg = sl ^ SW3(row);                                                \
      gld16(Wf + (size_t)(bn + row) * 1024 + k0 + kg * 8,                    \
            Bs + (bb) * 8192 + rbase * 64);                                  \
    }                                                                        \
  }

  float4 areg[2][4];
  F1ALOAD(areg[0], 0);
  F1BISS(0, 0);
  asm volatile("" ::: "memory");
  F1ALOAD(areg[1], 1);
  F1BISS(1, 1);

#pragma unroll
  for (int i = 0; i < 16; ++i) {
    const int cur = i & 1;
    if (i == 15) {
      asm volatile("s_waitcnt vmcnt(0)" ::: "memory");
    } else if (i < 7) {
      asm volatile("s_waitcnt vmcnt(8)" ::: "memory");
    } else {
      asm volatile("s_waitcnt vmcnt(6)" ::: "memory");
    }
    if (i < 8) {  // cvt fp32 A chunk i -> As[cur]
      __align__(16) us16 vv[16];
#pragma unroll
      for (int q = 0; q < 4; ++q)
#pragma unroll
        for (int j = 0; j < 4; ++j)
          vv[q * 4 + j] = f2bf(((const float*)&areg[cur][q])[j]);
      us16* base = As + cur * 4096 + arow * 64;
      *(short8*)(base + ((s0 ^ SW3(arow)) * 8)) = *(short8*)&vv[0];
      *(short8*)(base + (((s0 + 1) ^ SW3(arow)) * 8)) = *(short8*)&vv[8];
      asm volatile("s_waitcnt lgkmcnt(0)" ::: "memory");
    }
    __builtin_amdgcn_s_barrier();
    asm volatile("" ::: "memory");
#pragma unroll
    for (int kh = 0; kh < 2; ++kh) {
      const int g = kh * 4 + quad;
      short8 a_[4], b_[2];
#pragma unroll
      for (int mt = 0; mt < 4; ++mt) {
        int r = mt * 16 + lane15;
        a_[mt] = *(const short8*)(As + cur * 4096 + r * 64 + (g ^ SW3(r)) * 8);
      }
#pragma unroll
      for (int nt = 0; nt < 2; ++nt) {
        int c = w * 32 + nt * 16 + lane15;
        b_[nt] = *(const short8*)(Bs + cur * 8192 + c * 64 + (g ^ SW3(c)) * 8);
      }
#pragma unroll
      for (int mt = 0; mt < 4; ++mt)
#pragma unroll
        for (int nt = 0; nt < 2; ++nt)
          acc[mt][nt] = __builtin_amdgcn_mfma_f32_16x16x32_bf16(
              a_[mt], b_[nt], acc[mt][nt], 0, 0, 0);
    }
    asm volatile("" ::: "memory");
    __builtin_amdgcn_s_barrier();
    asm volatile("" ::: "memory");
    if (i + 2 < 16) {
      if (i + 2 < 8) {
        F1ALOAD(areg[cur], i + 2);
        F1BISS(i + 2, cur);
      } else {
        F1AGLD(i + 2, cur);
        F1BISS(i + 2, cur);
      }
    }
  }
#undef F1ALOAD
#undef F1AGLD
#undef F1BISS

  // epilogue: fp32 out + BN1 stats
#pragma unroll
  for (int nt = 0; nt < 2; ++nt) {
    int col = bn + w * 32 + nt * 16 + lane15;
    float bv = b1p[col];
    float s = 0.f, qq = 0.f;
#pragma unroll
    for (int mt = 0; mt < 4; ++mt) {
      int row0 = bm + mt * 16 + quad * 4;
#pragma unroll
      for (int r = 0; r < 4; ++r) {
        float val = acc[mt][nt][r] + bv;
        X1[(size_t)(row0 + r) * 512 + col] = val;
        s += val; qq = fmaf(val, val, qq);
      }
    }
    s += __shfl_xor(s, 16); s += __shfl_xor(s, 32);
    qq += __shfl_xor(qq, 16); qq += __shfl_xor(qq, 32);
    if (quad == 0) {
      atomicAdd(&st1[col], s);
      atomicAdd(&st1[512 + col], qq);
    }
  }
}

// ---------------------------------------------------------------------------
// gemm_ffn2bn (R7-verified, 64-row tiles, grid 376): FFN2 with BN1+ReLU
// fused into A-staging. K = 512 (nk = 8), 8 vm ops/chunk, vmcnt(8).
// ---------------------------------------------------------------------------
__global__ __launch_bounds__(256) void gemm_ffn2bn(
    const float* __restrict__ X1, const us16* __restrict__ W,
    const float* __restrict__ st1, const float* __restrict__ g1,
    const float* __restrict__ be1, const float* __restrict__ b2,
    float* __restrict__ X2, float* __restrict__ st2, int M, float invM) {
  __shared__ __align__(16) us16 As[2 * 64 * 64];    // 16 KB
  __shared__ __align__(16) us16 Bs[2 * 128 * 64];   // 32 KB
  __shared__ float slt[512], tlt[512];              //  4 KB
  int b = blockIdx.x;
  int i0 = (b & 7) * ((int)gridDim.x >> 3) + (b >> 3);  // XCD-contiguous
  const int bx = i0 >> 2, by = i0 & 3;
  const int t = threadIdx.x, w = t >> 6, lane = t & 63;
  const int lane15 = lane & 15, quad = lane >> 4;
  const int bm = bx * 64, bn = by * 128;
  const int lrow = lane >> 3, sl = lane & 7;
  const int arow = t >> 2, ac4 = (t & 3) * 16, s0 = (t & 3) * 2;

  for (int c = t; c < 512; c += 256) {
    float mean = st1[c] * invM;
    float var = fmaf(-mean, mean, st1[512 + c] * invM);
    float inv = rsqrtf(var + 1e-5f) * g1[c];
    slt[c] = inv;
    tlt[c] = be1[c] - mean * inv;
  }
  __syncthreads();

  floatx4 acc[4][2];
#pragma unroll
  for (int a = 0; a < 4; ++a)
#pragma unroll
    for (int c = 0; c < 2; ++c) acc[a][c] = (floatx4){0.f, 0.f, 0.f, 0.f};

#define ALOAD(dst, ii)                                                       \
  {                                                                          \
    const float* p_ = X1 + (size_t)(bm + arow) * 512 + ((ii) << 6) + ac4;    \
    dst[0] = *(const float4*)(p_);                                           \
    dst[1] = *(const float4*)(p_ + 4);                                       \
    dst[2] = *(const float4*)(p_ + 8);                                       \
    dst[3] = *(const float4*)(p_ + 12);                                      \
  }
#define BISSUE(ii, bb)                                                       \
  {                                                                          \
    int k0 = (ii) << 6;                                                      \
    _Pragma("unroll")                                                        \
    for (int p = 0; p < 4; ++p) {                                            \
      int rbase = p * 32 + w * 8;                                            \
      int row = rbase + lrow;                                                \
      int kg = sl ^ SW3(row);                                                \
      gld16(W + (size_t)(bn + row) * 512 + k0 + kg * 8,                      \
            Bs + (bb) * 8192 + rbase * 64);                                  \
    }                                                                        \
  }

  float4 areg[2][4];
  ALOAD(areg[0], 0);
  BISSUE(0, 0);
  asm volatile("" ::: "memory");
  ALOAD(areg[1], 1);
  BISSUE(1, 1);

#pragma unroll
  for (int i = 0; i < 8; ++i) {
    const int cur = i & 1;
    if (i + 1 < 8) {
      asm volatile("s_waitcnt vmcnt(8)" ::: "memory");
    } else {
      asm volatile("s_waitcnt vmcnt(0)" ::: "memory");
    }
    {
      const int k0 = i << 6;
      __align__(16) us16 vv[16];
#pragma unroll
      for (int q = 0; q < 4; ++q) {
#pragma unroll
        for (int j = 0; j < 4; ++j) {
          int c = k0 + ac4 + q * 4 + j;
          float x = ((const float*)&areg[cur][q])[j];
          float y = fmaxf(fmaf(x, slt[c], tlt[c]), 0.f);
          vv[q * 4 + j] = f2bf(y);
        }
      }
      us16* base = As + cur * 4096 + arow * 64;
      *(short8*)(base + ((s0 ^ SW3(arow)) * 8)) = *(short8*)&vv[0];
      *(short8*)(base + (((s0 + 1) ^ SW3(arow)) * 8)) = *(short8*)&vv[8];
    }
    asm volatile("s_waitcnt lgkmcnt(0)" ::: "memory");
    __builtin_amdgcn_s_barrier();
    asm volatile("" ::: "memory");
#pragma unroll
    for (int kh = 0; kh < 2; ++kh) {
      const int g = kh * 4 + quad;
      short8 a_[4], b_[2];
#pragma unroll
      for (int mt = 0; mt < 4; ++mt) {
        int r = mt * 16 + lane15;
        a_[mt] = *(const short8*)(As + cur * 4096 + r * 64 + (g ^ SW3(r)) * 8);
      }
#pragma unroll
      for (int nt = 0; nt < 2; ++nt) {
        int c = w * 32 + nt * 16 + lane15;
        b_[nt] = *(const short8*)(Bs + cur * 8192 + c * 64 + (g ^ SW3(c)) * 8);
      }
#pragma unroll
      for (int mt = 0; mt < 4; ++mt)
#pragma unroll
        for (int nt = 0; nt < 2; ++nt)
          acc[mt][nt] = __builtin_amdgcn_mfma_f32_16x16x32_bf16(
              a_[mt], b_[nt], acc[mt][nt], 0, 0, 0);
    }
    asm volatile("" ::: "memory");
    __builtin_amdgcn_s_barrier();
    asm volatile("" ::: "memory");
    if (i + 2 < 8) {
      ALOAD(areg[cur], i + 2);
      BISSUE(i + 2, cur);
    }
  }
#undef ALOAD
#undef BISSUE

#pragma unroll
  for (int nt = 0; nt < 2; ++nt) {
    int col = bn + w * 32 + nt * 16 + lane15;
    float bv = b2[col];
    float s = 0.f, qq = 0.f;
#pragma unroll
    for (int mt = 0; mt < 4; ++mt) {
      int row0 = bm + mt * 16 + quad * 4;
#pragma unroll
      for (int r = 0; r < 4; ++r) {
        float val = acc[mt][nt][r] + bv;
        X2[(size_t)(row0 + r) * 512 + col] = val;
        s += val; qq = fmaf(val, val, qq);
      }
    }
    s += __shfl_xor(s, 16); s += __shfl_xor(s, 32);
    qq += __shfl_xor(qq, 16); qq += __shfl_xor(qq, 32);
    if (quad == 0) {
      atomicAdd(&st2[col], s);
      atomicAdd(&st2[512 + col], qq);
    }
  }
}

// ---------------------------------------------------------------------------
// attn_v6: 4 waves x 16 dst rows of one (b,h). Batch offsets from precomputed
// prefix table (prep0) instead of a serial 16-load loop per block.
// ---------------------------------------------------------------------------
__global__ __launch_bounds__(256) void attn_v6(
    const us16* __restrict__ Qh, const us16* __restrict__ Kh,
    const us16* __restrict__ Vt, const int* __restrict__ dlens,
    const int* __restrict__ slens, const int* __restrict__ offs,
    us16* __restrict__ O, int Md, int Ms) {
  const int b = blockIdx.x, h = blockIdx.y, tile = blockIdx.z;
  const int doff = offs[b], soff = offs[16 + b];
  const int dlen = dlens[b], slen = slens[b];
  if (tile * 64 >= dlen) return;

  __shared__ __align__(16) us16 Ks[2 * 64 * 64];   // 16 KB
  __shared__ __align__(16) us16 Vts[2 * 64 * 64];  // 16 KB
  __shared__ __align__(16) us16 Pw[4][16 * 72];

  const int t = threadIdx.x, wv = t >> 6, lane = t & 63;
  const int lane15 = lane & 15, quad = lane >> 4;
  const int i0w = tile * 64 + wv * 16;
  const bool active = i0w < dlen;  // dlen % 16 == 0

  const us16* Qp = Qh + ((size_t)(doff + (active ? i0w : 0))) * 512 + h * 64;
  const us16* Kp = Kh + ((size_t)soff) * 512 + h * 64;
  const us16* Vtp = Vt + ((size_t)h * 64) * Ms + soff;

  short8 af0 = *(const short8*)(Qp + (size_t)lane15 * 512 + quad * 8);
  short8 af1 = *(const short8*)(Qp + (size_t)lane15 * 512 + 32 + quad * 8);

  floatx4 oa[4];
#pragma unroll
  for (int nt = 0; nt < 4; ++nt) oa[nt] = (floatx4){0.f, 0.f, 0.f, 0.f};
  float m_r[4] = {-3.0e38f, -3.0e38f, -3.0e38f, -3.0e38f};
  float l_r[4] = {0.f, 0.f, 0.f, 0.f};

  const int nc = (slen + 63) >> 6;

#define KVST(c, bu)                                                       \
  {                                                                       \
    int jb = (c) << 6;                                                    \
    _Pragma("unroll")                                                     \
    for (int p = 0; p < 2; ++p) {                                         \
      int row = wv * 16 + p * 8 + (lane >> 3);                            \
      int slt = lane & 7;                                                 \
      int kg = slt ^ SW3(row);                                            \
      gld16(Kp + (size_t)(jb + row) * 512 + kg * 8,                       \
            Ks + (bu) * 4096 + (wv * 16 + p * 8) * 64);                   \
      gld16(Vtp + (size_t)row * Ms + jb + kg * 8,                         \
            Vts + (bu) * 4096 + (wv * 16 + p * 8) * 64);                  \
    }                                                                     \
  }

  KVST(0, 0);
  if (nc > 1) KVST(1, 1);
  for (int c = 0; c < nc; ++c) {
    const int cur = c & 1;
    if (c + 1 < nc) {
      asm volatile("s_waitcnt vmcnt(4)" ::: "memory");
    } else {
      asm volatile("s_waitcnt vmcnt(0)" ::: "memory");
    }
    __builtin_amdgcn_s_barrier();
    asm volatile("" ::: "memory");

    if (active) {
      const int j0 = c << 6;
      floatx4 s[4];
#pragma unroll
      for (int jt = 0; jt < 4; ++jt) {
        int j = jt * 16 + lane15;
        short8 b0 = *(const short8*)(Ks + cur * 4096 + j * 64 + ((quad ^ SW3(j)) * 8));
        short8 b1 = *(const short8*)(Ks + cur * 4096 + j * 64 + (((4 + quad) ^ SW3(j)) * 8));
        floatx4 a = (floatx4){0.f, 0.f, 0.f, 0.f};
        a = __builtin_amdgcn_mfma_f32_16x16x32_bf16(af0, b0, a, 0, 0, 0);
        a = __builtin_amdgcn_mfma_f32_16x16x32_bf16(af1, b1, a, 0, 0, 0);
        s[jt] = a;
      }
      float mx[4] = {-3.0e38f, -3.0e38f, -3.0e38f, -3.0e38f};
#pragma unroll
      for (int jt = 0; jt < 4; ++jt) {
        bool valid = (j0 + jt * 16 + lane15) < slen;
#pragma unroll
        for (int r = 0; r < 4; ++r) {
          float v = valid ? s[jt][r] * 0.125f : -3.0e38f;
          s[jt][r] = v;
          mx[r] = fmaxf(mx[r], v);
        }
      }
#pragma unroll
      for (int r = 0; r < 4; ++r) {
        mx[r] = fmaxf(mx[r], __shfl_xor(mx[r], 1));
        mx[r] = fmaxf(mx[r], __shfl_xor(mx[r], 2));
        mx[r] = fmaxf(mx[r], __shfl_xor(mx[r], 4));
        mx[r] = fmaxf(mx[r], __shfl_xor(mx[r], 8));
      }
      float al[4], sum[4];
#pragma unroll
      for (int r = 0; r < 4; ++r) {
        float mn = fmaxf(m_r[r], mx[r]);
        al[r] = __expf(m_r[r] - mn);
        m_r[r] = mn;
        sum[r] = 0.f;
      }
#pragma unroll
      for (int jt = 0; jt < 4; ++jt)
#pragma unroll
        for (int r = 0; r < 4; ++r) {
          float e = __expf(s[jt][r] - m_r[r]);
          sum[r] += e;
          Pw[wv][(quad * 4 + r) * 72 + jt * 16 + lane15] = f2bf(e);
        }
#pragma unroll
      for (int r = 0; r < 4; ++r) {
        sum[r] += __shfl_xor(sum[r], 1);
        sum[r] += __shfl_xor(sum[r], 2);
        sum[r] += __shfl_xor(sum[r], 4);
        sum[r] += __shfl_xor(sum[r], 8);
        l_r[r] = l_r[r] * al[r] + sum[r];
      }
#pragma unroll
      for (int nt = 0; nt < 4; ++nt)
#pragma unroll
        for (int r = 0; r < 4; ++r) oa[nt][r] *= al[r];
      short8 pa0 = *(const short8*)(&Pw[wv][lane15 * 72 + quad * 8]);
      short8 pa1 = *(const short8*)(&Pw[wv][lane15 * 72 + 32 + quad * 8]);
#pragma unroll
      for (int nt = 0; nt < 4; ++nt) {
        int d = nt * 16 + lane15;
        short8 v0 = *(const short8*)(Vts + cur * 4096 + d * 64 + ((quad ^ SW3(d)) * 8));
        short8 v1 = *(const short8*)(Vts + cur * 4096 + d * 64 + (((4 + quad) ^ SW3(d)) * 8));
        oa[nt] = __builtin_amdgcn_mfma_f32_16x16x32_bf16(pa0, v0, oa[nt], 0, 0, 0);
        oa[nt] = __builtin_amdgcn_mfma_f32_16x16x32_bf16(pa1, v1, oa[nt], 0, 0, 0);
      }
    }

    asm volatile("" ::: "memory");
    __builtin_amdgcn_s_barrier();
    asm volatile("" ::: "memory");
    if (c + 2 < nc) KVST(c + 2, cur);
  }
#undef KVST

  if (active) {
    float linv[4];
#pragma unroll
    for (int r = 0; r < 4; ++r) linv[r] = 1.f / l_r[r];
#pragma unroll
    for (int r = 0; r < 4; ++r) {
      int i = quad * 4 + r;
      us16* orow = O + (size_t)(doff + i0w + i) * H_DIM + h * 64;
#pragma unroll
      for (int nt = 0; nt < 4; ++nt) {
        int d = nt * 16 + lane15;
        orow[d] = f2bf(oa[nt][r] * linv[r]);
      }
    }
  }
}

// ---------------------------------------------------------------------------
// bn2_apply: BN2 + residual -> fp32 out. Per-column affine tables built
// once in LDS (same fmaf formulation as gemm_ffn2bn's verified BN1 path);
// removes 2 stat loads + rsqrtf per element from the memory-bound loop.
// ---------------------------------------------------------------------------
__global__ __launch_bounds__(256) void bn2_apply(
    const float* __restrict__ X, const float* __restrict__ stats,
    const float* __restrict__ g, const float* __restrict__ be,
    const float* __restrict__ resid, float* __restrict__ Y,
    int M, float invM) {
  __shared__ float sl[512], tl[512];
  for (int c = threadIdx.x; c < 512; c += 256) {
    float mean = stats[c] * invM;
    float var = fmaf(-mean, mean, stats[512 + c] * invM);
    float inv = rsqrtf(var + 1e-5f) * g[c];
    sl[c] = inv;
    tl[c] = be[c] - mean * inv;
  }
  __syncthreads();
  const size_t total4 = (size_t)M * (H_DIM / 4);
  for (size_t i = (size_t)blockIdx.x * 256 + threadIdx.x; i < total4;
       i += (size_t)gridDim.x * 256) {
    int c = (int)((i * 4) & (H_DIM - 1));
    float4 x = ((const float4*)X)[i];
    float4 rr = ((const float4*)resid)[i];
    float4 o;
    o.x = fmaf(x.x, sl[c], tl[c]) + rr.x;
    o.y = fmaf(x.y, sl[c + 1], tl[c + 1]) + rr.y;
    o.z = fmaf(x.z, sl[c + 2], tl[c + 2]) + rr.z;
    o.w = fmaf(x.w, sl[c + 3], tl[c + 3]) + rr.w;
    ((float4*)Y)[i] = o;
  }
}

// ---------------------------------------------------------------------------
extern "C" void kernel_launch(void* const* d_in, const int* in_sizes, int n_in,
                              void* d_out, int out_size, void* d_ws, size_t ws_size,
                              hipStream_t stream) {
  const float* src_h = (const float*)d_in[0];
  const float* dst_h = (const float*)d_in[1];
  const int* s_lens  = (const int*)d_in[2];
  const int* d_lens  = (const int*)d_in[3];
  const float* Wq = (const float*)d_in[4];  const float* bq = (const float*)d_in[5];
  const float* Wk = (const float*)d_in[6];  const float* bk = (const float*)d_in[7];
  const float* Wv = (const float*)d_in[8];  const float* bv = (const float*)d_in[9];
  const float* Wm = (const float*)d_in[10]; const float* bm = (const float*)d_in[11];
  const float* W1 = (const float*)d_in[12]; const float* b1 = (const float*)d_in[13];
  const float* g1 = (const float*)d_in[14]; const float* be1 = (const float*)d_in[15];
  const float* W2 = (const float*)d_in[16]; const float* b2 = (const float*)d_in[17];
  const float* g2 = (const float*)d_in[18]; const float* be2 = (const float*)d_in[19];

  const int total_src = in_sizes[0] / H_DIM;  // 7232 = 113*64
  const int total_dst = in_sizes[1] / H_DIM;  // 6016 = 94*64

  // ---- workspace layout (byte offsets); peak ~30.3 MB ----
  char* ws = (char*)d_ws;
  us16* wbf  = (us16*)(ws + 0);              // 3,145,728 weights bf16
  float* b1p = (float*)(ws + 3145728);       // 2,048
  float* st  = (float*)(ws + 3147776);       // 8,192
  us16* Qh   = (us16*)(ws + 3155968);        // 6,160,384
  us16* Kh   = (us16*)(ws + 9316352);        // 7,405,568
  us16* Vt   = (us16*)(ws + 16721920);       // 7,405,568
  us16* Ob   = (us16*)(ws + 24127488);       // 6,160,384 (ends 30,287,872)
  int* offs  = (int*)(ws + 30287872);        // 128 (batch prefix offsets)
  float* X1  = (float*)(ws + 3155968);       // 12,320,768 (aliases Qh+Kh, dead)
  float* X2  = (float*)(ws + 16721920);      // 12,320,768 (aliases Vt+Ob head;
                                             //  Ob dead after FFN1 reads)
  float* st1 = st, *st2 = st + 1024;

  us16* Wqb = wbf;                 // 262144 elems (rows permuted head-major)
  us16* Wkv = wbf + 262144;        // 524288 (Wk rows permuted, then Wv rows)
  us16* Wf  = wbf + 786432;        // 524288 ([W1a | Wc-perm] rows of 1024)
  us16* W2b = wbf + 1310720;       // 262144

  const int mbd = total_dst / 64;  // 94
  const int mbs = total_src / 64;  // 113
  const int ngemm = mbd * 4 + mbs * 8;  // 1280
  const dim3 blk256(256);
  const float invM = 1.f / (float)total_dst;

  // 1: QKV weight casts + stat zero + batch offset prefix (small: 3 MB)
  prep0<<<dim3(768), blk256, 0, stream>>>(
      Wq, Wk, Wv, d_lens, s_lens, Wqb, Wkv, st, offs);

  // 2: Q + fused K/V projections (fp32-A reg-staged) + FFN-weight prep
  gemm_qkv<<<dim3(ngemm + 194), blk256, 0, stream>>>(
      dst_h, src_h, Wqb, Wkv, bq, bk, bv, Qh, Kh, Vt,
      W1, Wm, W2, b1, bm, Wf, W2b, b1p, total_dst, total_src);

  // 3: attention -> Ob (bf16 [M,512] head-major)
  attn_v6<<<dim3(NBATCH, N_HEADS, 8), blk256, 0, stream>>>(
      Qh, Kh, Vt, d_lens, s_lens, offs, Ob, total_dst, total_src);

  // 4: FFN1 mixed-A (64-row tiles, R7-verified): -> X1 + BN1 stats
  gemm_ffn1<<<dim3(mbd * 4), blk256, 0, stream>>>(
      dst_h, Ob, Wf, b1p, X1, st1, total_dst);

  // 5: FFN2 + fused BN1+ReLU (64-row tiles, R7-verified) -> X2 + BN2 stats
  gemm_ffn2bn<<<dim3(mbd * 4), blk256, 0, stream>>>(
      X1, W2b, st1, g1, be1, b2, X2, st2, total_dst, invM);

  // 6: BN2 + residual -> d_out (fp32, float4, LDS tables, 2048 blocks)
  bn2_apply<<<dim3(2048), blk256, 0, stream>>>(
      X2, st2, g2, be2, dst_h, (float*)d_out, total_dst, invM);
}